// Round 2
// baseline (239.334 us; speedup 1.0000x reference)
//
#include <hip/hip_runtime.h>

#define B_NUM 64
#define C_NUM 4
#define J_NUM 17
#define HH 96
#define WW 96
#define HWSZ (HH * WW)   // 9216

__device__ __forceinline__ float waveMax(float v) {
#pragma unroll
  for (int o = 32; o > 0; o >>= 1) v = fmaxf(v, __shfl_xor(v, o));
  return v;
}
__device__ __forceinline__ float waveSum(float v) {
#pragma unroll
  for (int o = 32; o > 0; o >>= 1) v += __shfl_xor(v, o);
  return v;
}

// One block (256 threads) per (bc, j) row of 9216 fp32.
__global__ __launch_bounds__(256) void softargmax_k(
    const float* __restrict__ hm, const int* __restrict__ Hp,
    const int* __restrict__ Wp, float* __restrict__ kp) {
  const int r = blockIdx.x;
  const int t = threadIdx.x;
  const float4* row = (const float4*)(hm + (size_t)r * HWSZ);

  float4 v[9];
  float m = -3.4e38f;
#pragma unroll
  for (int k = 0; k < 9; ++k) {
    v[k] = row[k * 256 + t];
    m = fmaxf(m, fmaxf(fmaxf(v[k].x, v[k].y), fmaxf(v[k].z, v[k].w)));
  }
  m = waveMax(m);
  __shared__ float smax[4];
  const int wid = t >> 6, lane = t & 63;
  if (lane == 0) smax[wid] = m;
  __syncthreads();
  m = fmaxf(fmaxf(smax[0], smax[1]), fmaxf(smax[2], smax[3]));
  const float M100 = 100.0f * m;

  float se = 0.f, sx = 0.f, sy = 0.f;
#pragma unroll
  for (int k = 0; k < 9; ++k) {
    const int base = k * 1024 + t * 4;  // 96 % 4 == 0 -> all 4 elems share h
    const float e0 = __expf(fmaf(100.f, v[k].x, -M100));
    const float e1 = __expf(fmaf(100.f, v[k].y, -M100));
    const float e2 = __expf(fmaf(100.f, v[k].z, -M100));
    const float e3 = __expf(fmaf(100.f, v[k].w, -M100));
    const int h = base / WW;
    const int w0 = base - h * WW;
    const float esum = (e0 + e1) + (e2 + e3);
    se += esum;
    sy += esum * (float)h;
    sx += e0 * (float)w0 + e1 * (float)(w0 + 1) + e2 * (float)(w0 + 2) +
          e3 * (float)(w0 + 3);
  }
  se = waveSum(se);
  sx = waveSum(sx);
  sy = waveSum(sy);
  __shared__ float ssum[4][3];
  if (lane == 0) {
    ssum[wid][0] = se;
    ssum[wid][1] = sx;
    ssum[wid][2] = sy;
  }
  __syncthreads();
  if (t == 0) {
    const float SE = (ssum[0][0] + ssum[1][0]) + (ssum[2][0] + ssum[3][0]);
    const float SX = (ssum[0][1] + ssum[1][1]) + (ssum[2][1] + ssum[3][1]);
    const float SY = (ssum[0][2] + ssum[1][2]) + (ssum[2][2] + ssum[3][2]);
    // reference: scale = [H_img/Hh, W_img/Wh], applied to (kx, ky) in order
    const float sc_x = (float)Hp[0] / (float)HH;
    const float sc_y = (float)Wp[0] / (float)WW;
    ((float2*)kp)[r] = make_float2(SX / SE * sc_x, SY / SE * sc_y);
  }
}

// One thread per (b, j): M = A^T A (double), Jacobi eigen 4x4, min eigvec.
__global__ __launch_bounds__(256) void dlt_k(
    const float* __restrict__ P, const float* __restrict__ conf,
    const float* __restrict__ kp, float* __restrict__ out) {
  const int idx = blockIdx.x * blockDim.x + threadIdx.x;
  if (idx >= B_NUM * J_NUM) return;
  const int b = idx / J_NUM;
  const int j = idx - b * J_NUM;

  double M[4][4];
#pragma unroll
  for (int a = 0; a < 4; ++a)
#pragma unroll
    for (int bb = 0; bb < 4; ++bb) M[a][bb] = 0.0;

#pragma unroll
  for (int c = 0; c < C_NUM; ++c) {
    const float* Pm = P + ((size_t)(b * C_NUM + c)) * 12;
    const float cf = conf[(b * C_NUM + c) * J_NUM + j];
    const float2 xy = ((const float2*)kp)[(b * C_NUM + c) * J_NUM + j];
    double row0[4], row1[4];
#pragma unroll
    for (int l = 0; l < 4; ++l) {
      const double p2 = (double)Pm[8 + l];
      row0[l] = (p2 * (double)xy.x - (double)Pm[l]) * (double)cf;
      row1[l] = (p2 * (double)xy.y - (double)Pm[4 + l]) * (double)cf;
    }
#pragma unroll
    for (int a = 0; a < 4; ++a)
#pragma unroll
      for (int bb = 0; bb < 4; ++bb)
        M[a][bb] += row0[a] * row0[bb] + row1[a] * row1[bb];
  }

  double V[4][4];
#pragma unroll
  for (int a = 0; a < 4; ++a)
#pragma unroll
    for (int bb = 0; bb < 4; ++bb) V[a][bb] = (a == bb) ? 1.0 : 0.0;

  for (int sweep = 0; sweep < 8; ++sweep) {
#pragma unroll
    for (int p = 0; p < 3; ++p) {
#pragma unroll
      for (int q = p + 1; q < 4; ++q) {
        const double d = M[p][q];
        if (fabs(d) < 1e-300) continue;
        const double a = M[p][p], bq = M[q][q];
        const double theta = (bq - a) / (2.0 * d);
        const double tt =
            (theta >= 0.0 ? 1.0 : -1.0) / (fabs(theta) + sqrt(theta * theta + 1.0));
        const double cc = 1.0 / sqrt(tt * tt + 1.0);
        const double ss = tt * cc;
#pragma unroll
        for (int k = 0; k < 4; ++k) {
          if (k == p || k == q) continue;
          const double mkp = M[k][p], mkq = M[k][q];
          M[k][p] = M[p][k] = cc * mkp - ss * mkq;
          M[k][q] = M[q][k] = ss * mkp + cc * mkq;
        }
        M[p][p] = a - tt * d;
        M[q][q] = bq + tt * d;
        M[p][q] = M[q][p] = 0.0;
#pragma unroll
        for (int k = 0; k < 4; ++k) {
          const double vkp = V[k][p], vkq = V[k][q];
          V[k][p] = cc * vkp - ss * vkq;
          V[k][q] = ss * vkp + cc * vkq;
        }
      }
    }
  }

  int mi = 0;
  double mv = M[0][0];
#pragma unroll
  for (int i = 1; i < 4; ++i)
    if (M[i][i] < mv) { mv = M[i][i]; mi = i; }
  const double h0 = V[0][mi], h1 = V[1][mi], h2 = V[2][mi], h3 = V[3][mi];
  out[idx * 3 + 0] = (float)(h0 / h3);
  out[idx * 3 + 1] = (float)(h1 / h3);
  out[idx * 3 + 2] = (float)(h2 / h3);
}

extern "C" void kernel_launch(void* const* d_in, const int* in_sizes, int n_in,
                              void* d_out, int out_size, void* d_ws, size_t ws_size,
                              hipStream_t stream) {
  const float* hm = (const float*)d_in[0];
  const float* P = (const float*)d_in[1];
  const float* conf = (const float*)d_in[2];
  const int* Hp = (const int*)d_in[3];
  const int* Wp = (const int*)d_in[4];
  float* out = (float*)d_out;
  float* kp = (float*)d_ws;  // 4352 float2 keypoints

  softargmax_k<<<B_NUM * C_NUM * J_NUM, 256, 0, stream>>>(hm, Hp, Wp, kp);
  dlt_k<<<(B_NUM * J_NUM + 255) / 256, 256, 0, stream>>>(P, conf, kp, out);
}